// Round 3
// baseline (102.242 us; speedup 1.0000x reference)
//
#include <hip/hip_runtime.h>
#include <cmath>

// Problem constants (from setup_inputs)
constexpr int Bk = 4;
constexpr int Nk = 300000;
constexpr int Kk = 64;
constexpr int BLOCK = 256;
constexpr int CHUNK = 4;                       // contiguous anchors per thread
constexpr int SUPER = BLOCK * CHUNK;           // 1024 anchors per block
constexpr int PBI = (Nk + SUPER - 1) / SUPER;  // 293 blocks per image
constexpr int NBLK = Bk * PBI;                 // 1172 blocks total

#define C_ALPHA 0.95f
#define C_NALPHA (1.0f - 0.95f)
#define C_DAMP 0.7f

// d_ws layout: float4 partial[NBLK] (cls, xy, ang, npos) — every slot written, no init needed

__global__ __launch_bounds__(BLOCK) void focal_main(
    const float* __restrict__ cls_,   // [B,N,C]
    const float* __restrict__ reg_,   // [B,N,3]
    const float* __restrict__ anc_,   // [B,N,3] (only image 0 used, per reference)
    const float* __restrict__ ann_,   // [B,K,4]
    float4* __restrict__ part)        // [NBLK]
{
    __shared__ float2 s_xy[Kk];
    __shared__ float  s_an[Kk];
    __shared__ float  s_cl[Kk];

    const int b   = blockIdx.x / PBI;
    const int blk = blockIdx.x - b * PBI;
    const int tid = threadIdx.x;
    const int a0  = blk * SUPER + tid * CHUNK;   // first anchor owned by this thread

    if (tid < Kk) {
        const float4 a4 = reinterpret_cast<const float4*>(ann_)[b * Kk + tid];
        s_xy[tid] = make_float2(a4.x, a4.y);
        s_an[tid] = a4.z;
        s_cl[tid] = a4.w;
    }
    __syncthreads();

    const bool full = (a0 + CHUNK) <= Nk;

    // ---- anchor loads: 3 contiguous float4s per thread (dense, coalesced) ----
    float ax[CHUNK], ay[CHUNK], aa[CHUNK];
    if (full) {
        const float4* a4p = reinterpret_cast<const float4*>(anc_);
        const int fb = 3 * (blk * BLOCK + tid);
        const float4 r0 = a4p[fb + 0];
        const float4 r1 = a4p[fb + 1];
        const float4 r2 = a4p[fb + 2];
        ax[0] = r0.x; ay[0] = r0.y; aa[0] = r0.z;
        ax[1] = r0.w; ay[1] = r1.x; aa[1] = r1.y;
        ax[2] = r1.z; ay[2] = r1.w; aa[2] = r2.x;
        ax[3] = r2.y; ay[3] = r2.z; aa[3] = r2.w;
    } else {
        #pragma unroll
        for (int c = 0; c < CHUNK; ++c) {
            const int n = a0 + c;
            if (n < Nk) {
                ax[c] = anc_[(size_t)n * 3 + 0];
                ay[c] = anc_[(size_t)n * 3 + 1];
                aa[c] = anc_[(size_t)n * 3 + 2];
            } else { ax[c] = 1e9f; ay[c] = 1e9f; aa[c] = 0.f; }
        }
    }

    // ---- issue cls loads early (4 contiguous float4s) so VMEM hides under argmin ----
    float4 p4[CHUNK];
    if (full) {
        const float4* c4 = reinterpret_cast<const float4*>(cls_) + (size_t)b * Nk + a0;
        #pragma unroll
        for (int c = 0; c < CHUNK; ++c) p4[c] = c4[c];
    } else {
        #pragma unroll
        for (int c = 0; c < CHUNK; ++c) {
            const int n = a0 + c;
            p4[c] = (n < Nk) ? reinterpret_cast<const float4*>(cls_)[(size_t)b * Nk + n]
                             : make_float4(0.5f, 0.5f, 0.5f, 0.5f);
        }
    }

    // ---- squared-distance argmin over K annotations (first-index-wins) ----
    float best[CHUNK];
    int   arg[CHUNK];
    #pragma unroll
    for (int c = 0; c < CHUNK; ++c) { best[c] = 3.4e38f; arg[c] = 0; }

    #pragma unroll
    for (int k = 0; k < Kk; ++k) {
        const float2 axy = s_xy[k];
        #pragma unroll
        for (int c = 0; c < CHUNK; ++c) {
            const float dx = ax[c] - axy.x;
            const float dy = ay[c] - axy.y;
            const float d  = fmaf(dy, dy, dx * dx);
            if (d < best[c]) { best[c] = d; arg[c] = k; }
        }
    }

    float cls_sum = 0.f, xy_sum = 0.f, ang_sum = 0.f, posn = 0.f;

    #pragma unroll
    for (int c = 0; c < CHUNK; ++c) {
        const bool  valid = full || (a0 + c < Nk);
        const int   a     = arg[c];
        const float aang  = fabsf(aa[c] - s_an[a]);
        const bool  posm  = valid && (best[c] < 900.0f)   && (aang < 20.0f);   // d < 30
        const bool  negm  = valid && ((best[c] >= 2025.0f) || (aang >= 30.0f)); // d >= 45
        posn += posm ? 1.0f : 0.0f;

        // focal BCE: base = all-classes target-0 form, then pos-class fixup
        const float p[4] = {p4[c].x, p4[c].y, p4[c].z, p4[c].w};
        float base = 0.f;
        #pragma unroll
        for (int cc = 0; cc < 4; ++cc) {
            const float pc = fminf(fmaxf(p[cc], 1e-4f), 1.0f - 1e-4f);
            base = fmaf(pc * pc, -__logf(1.0f - pc), base);
        }
        float s = C_NALPHA * base;
        if (posm) {
            const int cidx = (int)s_cl[a];
            float pc = (cidx < 2) ? (cidx == 0 ? p[0] : p[1])
                                  : (cidx == 2 ? p[2] : p[3]);
            pc = fminf(fmaxf(pc, 1e-4f), 1.0f - 1e-4f);
            s -= C_NALPHA * pc * pc * (-__logf(1.0f - pc));
            const float q = 1.0f - pc;
            s += C_ALPHA * q * q * (-__logf(pc));
        }
        cls_sum += (posm || negm) ? s * C_DAMP : 0.f;

        // regression losses, positives only (lazy scalar loads — ~10% of lanes)
        if (posm) {
            const size_t rb = ((size_t)b * Nk + (a0 + c)) * 3;
            const float rx = reg_[rb + 0];
            const float ry = reg_[rb + 1];
            const float ra = reg_[rb + 2];
            const float tx = s_xy[a].x - ax[c];
            const float ty = s_xy[a].y - ay[c];
            const float ta = s_an[a]   - aa[c];
            const float d0 = fabsf(tx - rx);
            const float d1 = fabsf(ty - ry);
            const float l0 = (d0 <= (1.0f / 9.0f)) ? 4.5f * d0 * d0 : d0 - (0.5f / 9.0f);
            const float l1 = (d1 <= (1.0f / 9.0f)) ? 4.5f * d1 * d1 : d1 - (0.5f / 9.0f);
            xy_sum += (l0 + l1) * C_DAMP;
            ang_sum += fmaxf((fabsf(ta - ra) - 10.0f) / 5.0f, 0.0f) * C_DAMP;
        }
    }

    // wave64 shuffle reduction, then cross-wave via LDS
    #pragma unroll
    for (int off = 32; off > 0; off >>= 1) {
        cls_sum += __shfl_down(cls_sum, off, 64);
        xy_sum  += __shfl_down(xy_sum,  off, 64);
        ang_sum += __shfl_down(ang_sum, off, 64);
        posn    += __shfl_down(posn,    off, 64);
    }
    __shared__ float r0s[4], r1s[4], r2s[4], r3s[4];
    const int wave = tid >> 6;
    const int lane = tid & 63;
    if (lane == 0) { r0s[wave] = cls_sum; r1s[wave] = xy_sum; r2s[wave] = ang_sum; r3s[wave] = posn; }
    __syncthreads();
    if (tid == 0) {
        part[blockIdx.x] = make_float4(r0s[0] + r0s[1] + r0s[2] + r0s[3],
                                       r1s[0] + r1s[1] + r1s[2] + r1s[3],
                                       r2s[0] + r2s[1] + r2s[2] + r2s[3],
                                       r3s[0] + r3s[1] + r3s[2] + r3s[3]);
    }
}

__global__ __launch_bounds__(256) void focal_finalize(
    const float4* __restrict__ part, float* __restrict__ out)
{
    const int b    = threadIdx.x >> 6;  // one wave per image
    const int lane = threadIdx.x & 63;
    double c = 0.0, x = 0.0, g = 0.0, q = 0.0;
    for (int i = lane; i < PBI; i += 64) {
        const float4 p = part[b * PBI + i];
        c += (double)p.x; x += (double)p.y; g += (double)p.z; q += (double)p.w;
    }
    #pragma unroll
    for (int off = 32; off > 0; off >>= 1) {
        c += __shfl_down(c, off, 64);
        x += __shfl_down(x, off, 64);
        g += __shfl_down(g, off, 64);
        q += __shfl_down(q, off, 64);
    }
    __shared__ double sc[4], sx[4], sg[4], sq[4];
    if (lane == 0) { sc[b] = c; sx[b] = x; sg[b] = g; sq[b] = q; }
    __syncthreads();
    if (threadIdx.x == 0) {
        double cm = 0.0, xm = 0.0, am = 0.0;
        for (int bb = 0; bb < Bk; ++bb) {
            const double np_   = sq[bb];
            const double denom = np_ > 1.0 ? np_ : 1.0;
            cm += sc[bb] / denom;
            if (np_ > 0.0) {
                xm += sx[bb] / (2.0 * denom);
                am += sg[bb] / denom;
            }
        }
        out[0] = (float)(cm / (double)Bk);
        out[1] = (float)(xm / (double)Bk);
        out[2] = (float)(am / (double)Bk);
    }
}

extern "C" void kernel_launch(void* const* d_in, const int* in_sizes, int n_in,
                              void* d_out, int out_size, void* d_ws, size_t ws_size,
                              hipStream_t stream)
{
    const float* cls_ = (const float*)d_in[0];
    const float* reg_ = (const float*)d_in[1];
    const float* anc_ = (const float*)d_in[2];
    const float* ann_ = (const float*)d_in[3];
    float4* part = (float4*)d_ws;

    focal_main<<<dim3(NBLK), dim3(BLOCK), 0, stream>>>(cls_, reg_, anc_, ann_, part);
    focal_finalize<<<dim3(1), dim3(256), 0, stream>>>(part, (float*)d_out);
}